// Round 15
// baseline (104.874 us; speedup 1.0000x reference)
//
#include <hip/hip_runtime.h>
#include <math.h>

#define IMG_H 512
#define IMG_W 512
#define PSIZE 512
#define NIMG 16
#define NBOX 16
#define RED_BLOCKS 256
#define Z0 4              // z-split for j=-1 (full-rect) tasks
#define SLOTS 20          // Z0 + 16 pair slots per (b,i)

// workspace layout (floats)
#define WS_PMEAN 0                      // 3
#define WS_PSTD  3                      // 3
#define WS_PART  6                      // 256*6 = 1536
#define WS_PAIR  1544                   // [bi][SLOTS][8]
#define WS_COEF  (1544 + 256 * SLOTS * 8)

typedef float f4u __attribute__((ext_vector_type(4), aligned(4)));
typedef float f2u __attribute__((ext_vector_type(2), aligned(4)));

struct BoxGeo { int y0, x0, ph, pw, valid; };

__device__ __forceinline__ BoxGeo make_geo(const float* bx) {
    float ymin = bx[0], xmin = bx[1], ymax = bx[2], xmax = bx[3];
    float h = ymax - ymin, w = xmax - xmin;
    float pwf = h * 0.3f;            // SCALE
    float phf = 1.0f * pwf;          // ASPECT * pw
    float oy = ymin + h * 0.5f;
    float ox = xmin + w * 0.5f;
    float yp = fmaxf(oy - phf * 0.5f, 0.0f);
    float xp = fmaxf(ox - pwf * 0.5f, 0.0f);
    if (yp + phf > (float)IMG_H) yp = (float)IMG_H - phf;
    if (xp + pwf > (float)IMG_W) xp = (float)IMG_W - pwf;
    BoxGeo g;
    g.y0 = (int)yp; g.x0 = (int)xp;   // tf.cast truncation
    g.ph = (int)phf; g.pw = (int)pwf;
    g.valid = (phf > 60.0f) ? 1 : 0;  // MIN_PATCH_H tested on float ph
    return g;
}

// vectorized bilinear: 4 memory requests instead of 12.
// x-neighbors are 6 contiguous floats -> dwordx4 + dwordx2 per row.
__device__ __forceinline__ void bsample_fast(const float* __restrict__ patch,
                                             int relY, int relX,
                                             float phf, float pwf, float s[3]) {
    float sy = ((float)relY + 0.5f) * (float)PSIZE / phf - 0.5f;
    sy = fminf(fmaxf(sy, 0.0f), (float)(PSIZE - 1));
    float sx = ((float)relX + 0.5f) * (float)PSIZE / pwf - 0.5f;
    sx = fminf(fmaxf(sx, 0.0f), (float)(PSIZE - 1));
    int y0 = (int)floorf(sy);
    int y1 = min(y0 + 1, PSIZE - 1);
    int x0 = (int)floorf(sx);
    float wy = sy - (float)y0;
    float wx = sx - (float)x0;
    const int baseX = min(x0, PSIZE - 2);
    const bool hi = (x0 == PSIZE - 1);         // wx == 0 in this case
    const float* r0 = patch + (y0 * PSIZE + baseX) * 3;
    const float* r1 = patch + (y1 * PSIZE + baseX) * 3;
    f4u a0 = *(const f4u*)r0; f2u b0 = *(const f2u*)(r0 + 4);
    f4u a1 = *(const f4u*)r1; f2u b1 = *(const f2u*)(r1 + 4);
    float p00c, p01c, p10c, p11c, top, bot;
    // c = 0
    p00c = hi ? a0.w : a0.x;  p01c = a0.w;
    p10c = hi ? a1.w : a1.x;  p11c = a1.w;
    top = (1.f - wx) * p00c + wx * p01c;
    bot = (1.f - wx) * p10c + wx * p11c;
    s[0] = (1.f - wy) * top + wy * bot;
    // c = 1
    p00c = hi ? b0.x : a0.y;  p01c = b0.x;
    p10c = hi ? b1.x : a1.y;  p11c = b1.x;
    top = (1.f - wx) * p00c + wx * p01c;
    bot = (1.f - wx) * p10c + wx * p11c;
    s[1] = (1.f - wy) * top + wy * bot;
    // c = 2
    p00c = hi ? b0.y : a0.z;  p01c = b0.y;
    p10c = hi ? b1.y : a1.z;  p11c = b1.y;
    top = (1.f - wx) * p00c + wx * p01c;
    bot = (1.f - wx) * p10c + wx * p11c;
    s[2] = (1.f - wy) * top + wy * bot;
}

template<int N, int NWAVES>
__device__ __forceinline__ void block_reduceN(float v[N]) {
    __shared__ float lds[NWAVES][N];
    const int lane = threadIdx.x & 63;
    const int wave = threadIdx.x >> 6;
    __syncthreads();
#pragma unroll
    for (int k = 0; k < N; ++k) {
#pragma unroll
        for (int off = 32; off > 0; off >>= 1)
            v[k] += __shfl_down(v[k], off, 64);
    }
    if (lane == 0) {
#pragma unroll
        for (int k = 0; k < N; ++k) lds[wave][k] = v[k];
    }
    __syncthreads();
    if (wave == 0) {
#pragma unroll
        for (int k = 0; k < N; ++k) {
            float x = (lane < NWAVES) ? lds[lane][k] : 0.0f;
#pragma unroll
            for (int off = 32; off > 0; off >>= 1)
                x += __shfl_down(x, off, 64);
            if (lane == 0) lds[0][k] = x;
        }
    }
    __syncthreads();
#pragma unroll
    for (int k = 0; k < N; ++k) v[k] = lds[0][k];
}

// ---------------------------------------------------------------------------
// patch mean/std
// ---------------------------------------------------------------------------
__global__ void patch_stats_partial(const float* __restrict__ patch,
                                    float* __restrict__ ws) {
    const int g = blockIdx.x * 256 + threadIdx.x;
    const float4* p4 = (const float4*)patch;
    float4 a = p4[3 * g], b = p4[3 * g + 1], c = p4[3 * g + 2];
    float v[6];
    v[0] = a.x + a.w + b.z + c.y;
    v[1] = a.y + b.x + b.w + c.z;
    v[2] = a.z + b.y + c.x + c.w;
    v[3] = a.x*a.x + a.w*a.w + b.z*b.z + c.y*c.y;
    v[4] = a.y*a.y + b.x*b.x + b.w*b.w + c.z*c.z;
    v[5] = a.z*a.z + b.y*b.y + c.x*c.x + c.w*c.w;
    block_reduceN<6, 4>(v);
    if (threadIdx.x == 0) {
        float* o = ws + WS_PART + blockIdx.x * 6;
#pragma unroll
        for (int k = 0; k < 6; ++k) o[k] = v[k];
    }
}

__global__ void patch_stats_final(float* __restrict__ ws) {
    float v[6];
    const float* p = ws + WS_PART + threadIdx.x * 6;
#pragma unroll
    for (int k = 0; k < 6; ++k) v[k] = p[k];
    block_reduceN<6, 4>(v);
    if (threadIdx.x == 0) {
        const float n = (float)(PSIZE * PSIZE);
#pragma unroll
        for (int c = 0; c < 3; ++c) {
            float m = v[c] / n;
            float var = v[3 + c] / n - m * m;
            ws[WS_PMEAN + c] = m;
            ws[WS_PSTD + c] = sqrtf(fmaxf(var, 0.f)) + 1e-6f;
        }
    }
}

// ---------------------------------------------------------------------------
// pair sums. grid (bi, j_idx 0..16, z 0..Z0-1); j>=1 uses only z==0.
// Early exits before any global load where possible.
// ---------------------------------------------------------------------------
__launch_bounds__(256)
__global__ void pair_sums(const float* __restrict__ images,
                          const float* __restrict__ boxes,
                          const float* __restrict__ patch,
                          float* __restrict__ ws) {
    const int bi = blockIdx.x;
    const int j_idx = blockIdx.y;
    const int z = blockIdx.z;
    const int b = bi >> 4, i = bi & 15;
    if (j_idx > i) return;                       // slot never read
    if (j_idx >= 1 && z > 0) return;             // no such slot

    const BoxGeo gi = make_geo(boxes + (b * NBOX + i) * 4);
    if (!gi.valid) return;                       // solve skips invalid i

    const int slot = (j_idx == 0) ? z : (Z0 + j_idx - 1);
    float* o = ws + WS_PAIR + ((size_t)bi * SLOTS + slot) * 8;

    int ry0 = gi.y0, rx0 = gi.x0;
    int ry1 = gi.y0 + gi.ph, rx1 = gi.x0 + gi.pw;
    int jy0 = 0, jx0 = 0, jph = -1;
    float jphf = 1.f, jpwf = 1.f;
    if (j_idx >= 1) {
        const BoxGeo gj = make_geo(boxes + (b * NBOX + j_idx - 1) * 4);
        if (!gj.valid) {
            if (threadIdx.x == 0) { for (int k = 0; k < 7; ++k) o[k] = 0.f; }
            return;
        }
        ry0 = max(ry0, gj.y0); rx0 = max(rx0, gj.x0);
        ry1 = min(ry1, gj.y0 + gj.ph); rx1 = min(rx1, gj.x0 + gj.pw);
        jy0 = gj.y0; jx0 = gj.x0; jph = gj.ph;
        jphf = (float)gj.ph; jpwf = (float)gj.pw;
    }
    const int rw = rx1 - rx0, rh = ry1 - ry0;
    if (rw <= 0 || rh <= 0) {
        if (threadIdx.x == 0) { for (int k = 0; k < 7; ++k) o[k] = 0.f; }
        return;
    }

    __shared__ BoxGeo geo[NBOX];
    if (threadIdx.x < NBOX)
        geo[threadIdx.x] = make_geo(boxes + (b * NBOX + threadIdx.x) * 4);
    __syncthreads();

    const int n = rw * rh;
    const float* img = images + (size_t)b * IMG_H * IMG_W * 3;
    const int nz = (j_idx == 0) ? Z0 : 1;

    float v[7] = {0.f, 0.f, 0.f, 0.f, 0.f, 0.f, 0.f};
    for (int t = z * 256 + threadIdx.x; t < n; t += 256 * nz) {
        const int y = ry0 + t / rw;
        const int x = rx0 + t % rw;
        bool inc = true;
        for (int k = j_idx; k < i; ++k) {        // k = j+1 .. i-1
            const BoxGeo gk = geo[k];
            if (gk.valid && y >= gk.y0 && y < gk.y0 + gk.ph &&
                x >= gk.x0 && x < gk.x0 + gk.pw) { inc = false; break; }
        }
        if (inc) {
            float s[3];
            if (jph > 0) {
                bsample_fast(patch, y - jy0, x - jx0, jphf, jpwf, s);
            } else {
                const float* p = img + ((size_t)y * IMG_W + x) * 3;
                s[0] = p[0]; s[1] = p[1]; s[2] = p[2];
            }
            v[0] += 1.f;
            v[1] += s[0]; v[2] += s[1]; v[3] += s[2];
            v[4] += s[0]*s[0]; v[5] += s[1]*s[1]; v[6] += s[2]*s[2];
        }
    }
    block_reduceN<7, 4>(v);
    if (threadIdx.x == 0) {
#pragma unroll
        for (int k = 0; k < 7; ++k) o[k] = v[k];
    }
}

// ---------------------------------------------------------------------------
// per-image 16-step recurrence. One wave per image.
// ---------------------------------------------------------------------------
__global__ void solve_coeffs(const float* __restrict__ boxes,
                             float* __restrict__ ws) {
    const int b = blockIdx.x;
    const int lane = threadIdx.x;       // 64 threads = 1 wave

    BoxGeo g = make_geo(boxes + (b * NBOX + (lane < NBOX ? lane : NBOX - 1)) * 4);
    float pm[3], ps[3];
#pragma unroll
    for (int c = 0; c < 3; ++c) { pm[c] = ws[WS_PMEAN + c]; ps[c] = ws[WS_PSTD + c]; }

    float sc[3] = {0.f, 0.f, 0.f}, of[3] = {0.f, 0.f, 0.f};

    for (int i = 0; i < NBOX; ++i) {
        const int valid_i = __shfl(g.valid, i, 64);
        if (!valid_i) continue;

        float cnt = 0.f, s1[3] = {0.f,0.f,0.f}, s2[3] = {0.f,0.f,0.f};
        if (lane <= i) {
            const int slot0 = (lane == 0) ? 0 : (Z0 + lane - 1);
            const int nz = (lane == 0) ? Z0 : 1;
            const float* p = ws + WS_PAIR +
                ((size_t)(b * NBOX + i) * SLOTS + slot0) * 8;
            for (int zz = 0; zz < nz; ++zz) {
                cnt   += p[zz*8 + 0];
                s1[0] += p[zz*8 + 1]; s1[1] += p[zz*8 + 2]; s1[2] += p[zz*8 + 3];
                s2[0] += p[zz*8 + 4]; s2[1] += p[zz*8 + 5]; s2[2] += p[zz*8 + 6];
            }
        }
        float ts[3], tq[3];
#pragma unroll
        for (int c = 0; c < 3; ++c) {
            if (lane == 0) { ts[c] = s1[c]; tq[c] = s2[c]; }
            else {
                ts[c] = sc[c] * s1[c] + of[c] * cnt;
                tq[c] = sc[c]*sc[c]*s2[c] + 2.f*sc[c]*of[c]*s1[c] + of[c]*of[c]*cnt;
            }
        }
#pragma unroll
        for (int c = 0; c < 3; ++c) {
#pragma unroll
            for (int off = 16; off > 0; off >>= 1) {
                ts[c] += __shfl_down(ts[c], off, 32);
                tq[c] += __shfl_down(tq[c], off, 32);
            }
        }
        const int phi = __shfl(g.ph, i, 64);
        const int pwi = __shfl(g.pw, i, 64);
        const float cntf = fmaxf((float)(phi * pwi), 1.0f);
        float nsc[3] = {0.f,0.f,0.f}, nof[3] = {0.f,0.f,0.f};
        if (lane == 0) {
#pragma unroll
            for (int c = 0; c < 3; ++c) {
                float mean = ts[c] / cntf;
                float var = tq[c] / cntf - mean * mean;
                float sd = sqrtf(fmaxf(var, 0.f)) + 1e-6f;
                nsc[c] = sd / ps[c];
                nof[c] = mean - pm[c] * nsc[c];
            }
        }
#pragma unroll
        for (int c = 0; c < 3; ++c) {
            float bs = __shfl(nsc[c], 0, 64);
            float bo = __shfl(nof[c], 0, 64);
            if (lane == i + 1) { sc[c] = bs; of[c] = bo; }
            if (lane == 0) {
                ws[WS_COEF + (size_t)(b * NBOX + i) * 8 + c] = bs;
                ws[WS_COEF + (size_t)(b * NBOX + i) * 8 + 3 + c] = bo;
            }
        }
    }
}

// ---------------------------------------------------------------------------
// render v4 = R9's v2 structure + bsample_fast.
// ---------------------------------------------------------------------------
__launch_bounds__(256)
__global__ void render(const float* __restrict__ images,
                       const float* __restrict__ boxes,
                       const float* __restrict__ patch,
                       const float* __restrict__ ws,
                       float* __restrict__ out) {
    const int b = blockIdx.y;
    const int tid = threadIdx.x;
    __shared__ BoxGeo geo[NBOX];
    __shared__ float coef[NBOX][6];
    __shared__ int smask;

    const int strip_y0 = blockIdx.x * 2;

    if (tid == 0) smask = 0;
    if (tid < NBOX)
        geo[tid] = make_geo(boxes + (b * NBOX + tid) * 4);
    if (tid < NBOX * 6) {
        int i = tid / 6, c = tid % 6;
        coef[i][c] = ws[WS_COEF + (size_t)(b * NBOX + i) * 8 + c];
    }
    __syncthreads();
    if (tid < NBOX) {
        const BoxGeo g = geo[tid];
        if (g.valid && g.y0 < strip_y0 + 2 && g.y0 + g.ph > strip_y0)
            atomicOr(&smask, 1 << tid);
    }
    __syncthreads();

    const int q = blockIdx.x * 256 + tid;
    const float4* src = (const float4*)(images + (size_t)b * IMG_H * IMG_W * 3);
    float4* dst = (float4*)(out + (size_t)b * IMG_H * IMG_W * 3);
    const int mask = smask;

    if (mask == 0) {                              // pure copy strip
        dst[3*q]     = src[3*q];
        dst[3*q + 1] = src[3*q + 1];
        dst[3*q + 2] = src[3*q + 2];
        return;
    }

    const int p0 = q << 2;
    const int y = p0 >> 9, x0 = p0 & 511;

    int last[4];
    bool any_un = false;
#pragma unroll
    for (int u = 0; u < 4; ++u) {
        const int x = x0 + u;
        int lj = -1;
        int m = mask;
        while (m) {
            const int j = 31 - __clz(m);
            const BoxGeo g = geo[j];
            if (y >= g.y0 && y < g.y0 + g.ph && x >= g.x0 && x < g.x0 + g.pw) {
                lj = j; break;
            }
            m &= ~(1 << j);
        }
        last[u] = lj;
        any_un |= (lj < 0);
    }

    float4 f[3];
    if (any_un) { f[0] = src[3*q]; f[1] = src[3*q + 1]; f[2] = src[3*q + 2]; }
    float* r = (float*)f;

#pragma unroll
    for (int u = 0; u < 4; ++u) {
        if (last[u] >= 0) {
            const BoxGeo g = geo[last[u]];
            float s[3];
            bsample_fast(patch, y - g.y0, (x0 + u) - g.x0,
                         (float)g.ph, (float)g.pw, s);
            r[3*u + 0] = s[0] * coef[last[u]][0] + coef[last[u]][3];
            r[3*u + 1] = s[1] * coef[last[u]][1] + coef[last[u]][4];
            r[3*u + 2] = s[2] * coef[last[u]][2] + coef[last[u]][5];
        }
    }
    dst[3*q] = f[0]; dst[3*q + 1] = f[1]; dst[3*q + 2] = f[2];
}

extern "C" void kernel_launch(void* const* d_in, const int* in_sizes, int n_in,
                              void* d_out, int out_size, void* d_ws, size_t ws_size,
                              hipStream_t stream) {
    const float* images = (const float*)d_in[0];
    const float* boxes  = (const float*)d_in[1];
    const float* patch  = (const float*)d_in[2];
    float* out = (float*)d_out;
    float* ws  = (float*)d_ws;

    patch_stats_partial<<<RED_BLOCKS, 256, 0, stream>>>(patch, ws);
    patch_stats_final<<<1, RED_BLOCKS, 0, stream>>>(ws);
    pair_sums<<<dim3(NIMG * NBOX, 17, Z0), 256, 0, stream>>>(images, boxes, patch, ws);
    solve_coeffs<<<NIMG, 64, 0, stream>>>(boxes, ws);
    render<<<dim3(IMG_H * IMG_W / 4 / 256, NIMG), 256, 0, stream>>>(images, boxes, patch, ws, out);
}